// Round 8
// baseline (290.957 us; speedup 1.0000x reference)
//
#include <hip/hip_runtime.h>
#include <hip/hip_bf16.h>

// Problem constants
static constexpr int Bc = 4;
static constexpr int Lc = 2048;
static constexpr int Cc = 512;     // FEATURE_DIM
static constexpr int Hc = 8;       // NUM_HEADS
static constexpr int Dc = 64;      // HEAD_DIM

using short8  = __attribute__((ext_vector_type(8))) short;
using float4v = __attribute__((ext_vector_type(4))) float;

static __device__ __forceinline__ unsigned short f2bf(float f) {
    __hip_bfloat16 h = __float2bfloat16(f);   // RNE
    return *reinterpret_cast<unsigned short*>(&h);
}
static __device__ __forceinline__ float bf2f(unsigned short u) {
    return __uint_as_float(((unsigned int)u) << 16);
}

// ---------------------------------------------------------------------------
// Kernel 0: prep (unchanged from R7).
// ---------------------------------------------------------------------------
__global__ __launch_bounds__(256) void prep_kernel(
    const float* __restrict__ ppg, const float* __restrict__ ecg,
    const float* __restrict__ Wq, const float* __restrict__ Wk,
    const float* __restrict__ Wv, const float* __restrict__ Wo,
    unsigned short* __restrict__ Xt_ppg, unsigned short* __restrict__ Xt_ecg,
    unsigned short* __restrict__ Wbf)
{
    __shared__ float Ts[64 * 69];
    const int task = blockIdx.x;
    const int tid  = threadIdx.x;

    if (task < 2048) {
        const int src = task >> 10;
        const int rem = task & 1023;
        const int b   = rem >> 8;
        const int c0  = ((rem >> 5) & 7) * 64;
        const int l0  = (rem & 31) * 64;
        const float* X = src ? ecg : ppg;
        unsigned short* Xt = src ? Xt_ecg : Xt_ppg;

        #pragma unroll
        for (int j = 0; j < 4; ++j) {
            int idx = tid + j * 256;
            int c = idx >> 4, l4 = idx & 15;
            float4 v = *(const float4*)(X + ((size_t)b * Cc + c0 + c) * Lc + l0 + l4 * 4);
            Ts[c * 69 + l4 * 4 + 0] = v.x;
            Ts[c * 69 + l4 * 4 + 1] = v.y;
            Ts[c * 69 + l4 * 4 + 2] = v.z;
            Ts[c * 69 + l4 * 4 + 3] = v.w;
        }
        __syncthreads();
        #pragma unroll
        for (int j = 0; j < 8; ++j) {
            int u = tid + j * 256;
            int l = u >> 5, p2 = u & 31;
            float a = Ts[(2 * p2) * 69 + l];
            float bb = Ts[(2 * p2 + 1) * 69 + l];
            ushort2 pk; pk.x = f2bf(a); pk.y = f2bf(bb);
            *(ushort2*)(Xt + ((size_t)b * Lc + l0 + l) * Cc + c0 + 2 * p2) = pk;
        }
    } else {
        const int wb   = task - 2048;
        const int widx = wb >> 7;
        const float* W = widx == 0 ? Wq : widx == 1 ? Wk : widx == 2 ? Wv : Wo;
        size_t off = (size_t)(wb & 127) * 2048 + (size_t)tid * 8;
        float4 v0 = *(const float4*)(W + off);
        float4 v1 = *(const float4*)(W + off + 4);
        unsigned short pk[8] = {f2bf(v0.x), f2bf(v0.y), f2bf(v0.z), f2bf(v0.w),
                                f2bf(v1.x), f2bf(v1.y), f2bf(v1.z), f2bf(v1.w)};
        *(short8*)(Wbf + (size_t)widx * Cc * Cc + off) = *(const short8*)pk;
    }
}

// ---------------------------------------------------------------------------
// Kernel 1: Q/K/V projections (unchanged from R7).
// ---------------------------------------------------------------------------
__global__ __launch_bounds__(256) void proj_kernel(
    const unsigned short* __restrict__ Xt_ppg,
    const unsigned short* __restrict__ Xt_ecg,
    const unsigned short* __restrict__ Wbf,
    const float* __restrict__ bq, const float* __restrict__ bk,
    const float* __restrict__ bv,
    unsigned short* __restrict__ Qw, unsigned short* __restrict__ Kw,
    unsigned short* __restrict__ Vtw)
{
    constexpr int LDW = 72;
    const int z = blockIdx.z, p = z >> 2, b = z & 3;
    const int l0 = blockIdx.x * 128, n0 = blockIdx.y * 128;
    const unsigned short* X = (p == 0) ? Xt_ppg : Xt_ecg;
    const unsigned short* W = Wbf + (size_t)p * Cc * Cc;
    const float* bias = (p == 0) ? bq : (p == 1) ? bk : bv;

    const int tid = threadIdx.x, wave = tid >> 6, lane = tid & 63;
    const int l16 = lane & 15, quad = lane >> 4;
    const int wr = wave >> 1, wc = wave & 1;

    __shared__ __align__(16) unsigned short At[128 * LDW];
    __shared__ __align__(16) unsigned short Bt[128 * LDW];

    float4v acc[4][4] = {};
    short8 areg[4], breg[4];

    const int srow = tid >> 3, sc8 = tid & 7;
    #pragma unroll
    for (int j = 0; j < 4; ++j) {
        areg[j] = *(const short8*)(X + ((size_t)b * Lc + l0 + srow + j * 32) * Cc + sc8 * 8);
        breg[j] = *(const short8*)(W + (size_t)(n0 + srow + j * 32) * Cc + sc8 * 8);
    }

    for (int c0 = 0; c0 < Cc; c0 += 64) {
        #pragma unroll
        for (int j = 0; j < 4; ++j) {
            *(short8*)&At[(srow + j * 32) * LDW + sc8 * 8] = areg[j];
            *(short8*)&Bt[(srow + j * 32) * LDW + sc8 * 8] = breg[j];
        }
        __syncthreads();

        if (c0 + 64 < Cc) {
            #pragma unroll
            for (int j = 0; j < 4; ++j) {
                areg[j] = *(const short8*)(X + ((size_t)b * Lc + l0 + srow + j * 32) * Cc
                                           + c0 + 64 + sc8 * 8);
                breg[j] = *(const short8*)(W + (size_t)(n0 + srow + j * 32) * Cc
                                           + c0 + 64 + sc8 * 8);
            }
        }

        const unsigned short* Am = (p < 2) ? At : Bt;
        const unsigned short* Bm = (p < 2) ? Bt : At;

        #pragma unroll
        for (int ks = 0; ks < 2; ++ks) {
            short8 bf[4];
            #pragma unroll
            for (int nt = 0; nt < 4; ++nt)
                bf[nt] = *(const short8*)&Bm[(wc * 64 + nt * 16 + l16) * LDW
                                             + ks * 32 + quad * 8];
            #pragma unroll
            for (int mt = 0; mt < 4; ++mt) {
                short8 af = *(const short8*)&Am[(wr * 64 + mt * 16 + l16) * LDW
                                                + ks * 32 + quad * 8];
                #pragma unroll
                for (int nt = 0; nt < 4; ++nt)
                    acc[mt][nt] = __builtin_amdgcn_mfma_f32_16x16x32_bf16(
                        af, bf[nt], acc[mt][nt], 0, 0, 0);
            }
        }
        __syncthreads();
    }

    if (p < 2) {
        const float sc = (p == 0) ? 0.18033688011112042f : 1.0f;  // 0.125*log2(e)
        unsigned short* dst = (p == 0) ? Qw : Kw;
        #pragma unroll
        for (int nt = 0; nt < 4; ++nt) {
            int n = n0 + wc * 64 + nt * 16 + l16;
            int h = n >> 6, d = n & 63;
            int bh = b * Hc + h;
            float bia = bias[n];
            #pragma unroll
            for (int mt = 0; mt < 4; ++mt) {
                #pragma unroll
                for (int r = 0; r < 4; ++r) {
                    int l = l0 + wr * 64 + mt * 16 + quad * 4 + r;
                    dst[((size_t)bh * Lc + l) * Dc + d] =
                        f2bf((acc[mt][nt][r] + bia) * sc);
                }
            }
        }
    } else {
        #pragma unroll
        for (int mt = 0; mt < 4; ++mt) {
            #pragma unroll
            for (int r = 0; r < 4; ++r) {
                int n = n0 + wr * 64 + mt * 16 + quad * 4 + r;
                int h = n >> 6, d = n & 63;
                int bh = b * Hc + h;
                float bia = bias[n];
                #pragma unroll
                for (int nt = 0; nt < 4; ++nt) {
                    int l = l0 + wc * 64 + nt * 16 + l16;
                    Vtw[((size_t)bh * Dc + d) * Lc + l] = f2bf(acc[mt][nt][r] + bia);
                }
            }
        }
    }
}

// ---------------------------------------------------------------------------
// Kernel 2: flash attention, split-K (2 splits), q=64/wave (qt=4), 256
// q/block, fused split-K combine via device-scope atomic counter.
// Per 64-key chunk per wave: 64 MFMA, 24 ds_read_b128, 16 ds_write_b64.
// ---------------------------------------------------------------------------
__global__ __launch_bounds__(256, 2) void attn_mfma_kernel(
    const unsigned short* __restrict__ Qg,    // [bh][l][64], pre-scaled
    const unsigned short* __restrict__ Kg,    // [bh][l][64]
    const unsigned short* __restrict__ Vtg,   // [bh][64][l]
    unsigned short* __restrict__ Opart0,      // [b][l][512] bf16 partial
    unsigned short* __restrict__ Opart1,
    float* __restrict__ lpart,                // [2][bh][l]
    unsigned short* __restrict__ ctx,         // [b][l][512] bf16 final
    int* __restrict__ ctr)                    // [bh][8] counters (zeroed)
{
    constexpr int LDW = 72;
    const int bh    = blockIdx.y;
    const int split = blockIdx.z;
    const int q0    = blockIdx.x * 256;
    const int tid   = threadIdx.x;
    const int wave  = tid >> 6;
    const int lane  = tid & 63;
    const int l16   = lane & 15;
    const int quad  = lane >> 4;

    __shared__ __align__(16) unsigned short Kt[64 * LDW];
    __shared__ __align__(16) unsigned short Vt[64 * LDW];
    __shared__ __align__(16) unsigned short PT[256 * LDW];  // Q stage, then P^T
    __shared__ int s_old;

    const int srow = tid >> 3, sc8 = tid & 7;

    // ---- stage Q tile (256 x 64) into PT ----
    const unsigned short* Qb = Qg + ((size_t)bh * Lc + q0) * Dc;
    #pragma unroll
    for (int j = 0; j < 8; ++j)
        *(short8*)&PT[(srow + j * 32) * LDW + sc8 * 8] =
            *(const short8*)(Qb + (srow + j * 32) * Dc + sc8 * 8);
    __syncthreads();

    // Q fragments (wave-private rows wave*64..+63; MFMA B-operand)
    short8 qf[4][2];
    #pragma unroll
    for (int qt = 0; qt < 4; ++qt)
        #pragma unroll
        for (int ks = 0; ks < 2; ++ks)
            qf[qt][ks] = *(const short8*)&PT[(wave * 64 + qt * 16 + l16) * LDW
                                             + ks * 32 + quad * 8];
    // PT rows are wave-private hereafter.

    float4v O[4][4] = {};                    // [qt][dt]; rows=q, cols=d
    float lsum[4] = {0.f, 0.f, 0.f, 0.f};

    const unsigned short* Kb0 = Kg + (size_t)bh * Lc * Dc;
    const unsigned short* Vb0 = Vtg + (size_t)bh * (Dc * Lc);
    const int kbase = split * (Lc / 2);

    short8 kreg[2], vreg[2];
    #pragma unroll
    for (int j = 0; j < 2; ++j) {
        kreg[j] = *(const short8*)(Kb0 + (size_t)(kbase + srow + j * 32) * Dc + sc8 * 8);
        vreg[j] = *(const short8*)(Vb0 + (size_t)(srow + j * 32) * Lc + kbase + sc8 * 8);
    }

    for (int kc = kbase; kc < kbase + Lc / 2; kc += 64) {
        #pragma unroll
        for (int j = 0; j < 2; ++j) {
            *(short8*)&Kt[(srow + j * 32) * LDW + sc8 * 8] = kreg[j];
            *(short8*)&Vt[(srow + j * 32) * LDW + sc8 * 8] = vreg[j];
        }
        __syncthreads();

        if (kc + 64 < kbase + Lc / 2) {
            #pragma unroll
            for (int j = 0; j < 2; ++j) {
                kreg[j] = *(const short8*)(Kb0 + (size_t)(kc + 64 + srow + j * 32) * Dc
                                           + sc8 * 8);
                vreg[j] = *(const short8*)(Vb0 + (size_t)(srow + j * 32) * Lc
                                           + kc + 64 + sc8 * 8);
            }
        }

        // ---- S^T = K·Q^T : 4 key-tiles x 4 query-tiles, af reused 4x ----
        float4v S[4][4];
        #pragma unroll
        for (int kt = 0; kt < 4; ++kt)
            #pragma unroll
            for (int qt = 0; qt < 4; ++qt)
                S[kt][qt] = (float4v){0.f, 0.f, 0.f, 0.f};
        #pragma unroll
        for (int ks = 0; ks < 2; ++ks) {
            #pragma unroll
            for (int kt = 0; kt < 4; ++kt) {
                short8 af = *(const short8*)&Kt[(kt * 16 + l16) * LDW
                                                + ks * 32 + quad * 8];
                #pragma unroll
                for (int qt = 0; qt < 4; ++qt)
                    S[kt][qt] = __builtin_amdgcn_mfma_f32_16x16x32_bf16(
                        af, qf[qt][ks], S[kt][qt], 0, 0, 0);
            }
        }

        // ---- P^T = exp2(S^T); accumulate l; store PT[q][key] ----
        #pragma unroll
        for (int qt = 0; qt < 4; ++qt) {
            #pragma unroll
            for (int kt = 0; kt < 4; ++kt) {
                float p0 = __builtin_amdgcn_exp2f(S[kt][qt][0]);
                float p1 = __builtin_amdgcn_exp2f(S[kt][qt][1]);
                float p2 = __builtin_amdgcn_exp2f(S[kt][qt][2]);
                float p3 = __builtin_amdgcn_exp2f(S[kt][qt][3]);
                lsum[qt] += (p0 + p1) + (p2 + p3);
                ushort4 pk;
                pk.x = f2bf(p0); pk.y = f2bf(p1); pk.z = f2bf(p2); pk.w = f2bf(p3);
                *(ushort4*)&PT[(wave * 64 + qt * 16 + l16) * LDW
                               + kt * 16 + quad * 4] = pk;
            }
        }

        // ---- O += P · V ----
        #pragma unroll
        for (int ks = 0; ks < 2; ++ks) {
            short8 pf[4];
            #pragma unroll
            for (int qt = 0; qt < 4; ++qt)
                pf[qt] = *(const short8*)&PT[(wave * 64 + qt * 16 + l16) * LDW
                                             + ks * 32 + quad * 8];
            #pragma unroll
            for (int dt = 0; dt < 4; ++dt) {
                short8 vf = *(const short8*)&Vt[(dt * 16 + l16) * LDW
                                                + ks * 32 + quad * 8];
                #pragma unroll
                for (int qt = 0; qt < 4; ++qt)
                    O[qt][dt] = __builtin_amdgcn_mfma_f32_16x16x32_bf16(
                        pf[qt], vf, O[qt][dt], 0, 0, 0);
            }
        }
        __syncthreads();
    }

    // ---- epilogue: write partial (bf16) + lpart; last block combines ----
    const int b = bh >> 3, h = bh & 7;
    unsigned short* Om = split ? Opart1 : Opart0;
    float* lp = lpart + (size_t)split * (Bc * Hc) * Lc + (size_t)bh * Lc;

    #pragma unroll
    for (int qt = 0; qt < 4; ++qt) {
        float t = lsum[qt];
        t += __shfl_xor(t, 16, 64);
        t += __shfl_xor(t, 32, 64);
        if (quad == 0)
            lp[q0 + wave * 64 + qt * 16 + l16] = t;
    }
    #pragma unroll
    for (int qt = 0; qt < 4; ++qt) {
        #pragma unroll
        for (int dt = 0; dt < 4; ++dt) {
            #pragma unroll
            for (int r = 0; r < 4; ++r) {
                int q = q0 + wave * 64 + qt * 16 + quad * 4 + r;
                Om[((size_t)b * Lc + q) * Cc + h * Dc + dt * 16 + l16] =
                    f2bf(O[qt][dt][r]);
            }
        }
    }

    __threadfence();                 // release: partials visible device-wide
    __syncthreads();                 // all threads' fences done before atomic
    if (tid == 0)
        s_old = atomicAdd(&ctr[bh * 8 + blockIdx.x], 1);
    __syncthreads();

    if (s_old == 1) {                // we are the last finisher: combine
        __threadfence();             // acquire: invalidate stale cache lines
        const unsigned short* Oo = split ? Opart0 : Opart1;
        const float* lp0 = lpart + (size_t)bh * Lc;
        const float* lp1 = lpart + (size_t)(Bc * Hc) * Lc + (size_t)bh * Lc;
        #pragma unroll
        for (int qt = 0; qt < 4; ++qt) {
            #pragma unroll
            for (int r = 0; r < 4; ++r) {
                int q = q0 + wave * 64 + qt * 16 + quad * 4 + r;
                float inv = 1.0f / (lp0[q] + lp1[q]);
                #pragma unroll
                for (int dt = 0; dt < 4; ++dt) {
                    size_t off = ((size_t)b * Lc + q) * Cc + h * Dc + dt * 16 + l16;
                    float other = bf2f(Oo[off]);
                    ctx[off] = f2bf((O[qt][dt][r] + other) * inv);
                }
            }
        }
    }
}

// ---------------------------------------------------------------------------
// Kernel 3: output projection, 128(l) x 128(n) tile, 2x2 wave quadrants
// (proj structure). D[n][l] = Wo·ctx^T; + bias + residual -> (B,C,L) fp32.
// ---------------------------------------------------------------------------
__global__ __launch_bounds__(256) void outproj_kernel(
    const unsigned short* __restrict__ ctx, const unsigned short* __restrict__ Wo_bf,
    const float* __restrict__ bo, const float* __restrict__ ppg,
    float* __restrict__ out)
{
    constexpr int LDW = 72;
    const int b = blockIdx.z;
    const int l0 = blockIdx.x * 128, n0 = blockIdx.y * 128;
    const int tid = threadIdx.x, wave = tid >> 6, lane = tid & 63;
    const int l16 = lane & 15, quad = lane >> 4;
    const int wr = wave >> 1, wc = wave & 1;

    __shared__ __align__(16) unsigned short At[128 * LDW];  // Wo tile [n][c]
    __shared__ __align__(16) unsigned short Bt[128 * LDW];  // ctx tile [l][c]

    float4v acc[4][4] = {};                  // [mt(n)][nt(l)]
    short8 areg[4], breg[4];

    const int srow = tid >> 3, sc8 = tid & 7;
    #pragma unroll
    for (int j = 0; j < 4; ++j) {
        areg[j] = *(const short8*)(Wo_bf + (size_t)(n0 + srow + j * 32) * Cc + sc8 * 8);
        breg[j] = *(const short8*)(ctx + ((size_t)b * Lc + l0 + srow + j * 32) * Cc + sc8 * 8);
    }

    for (int c0 = 0; c0 < Cc; c0 += 64) {
        #pragma unroll
        for (int j = 0; j < 4; ++j) {
            *(short8*)&At[(srow + j * 32) * LDW + sc8 * 8] = areg[j];
            *(short8*)&Bt[(srow + j * 32) * LDW + sc8 * 8] = breg[j];
        }
        __syncthreads();

        if (c0 + 64 < Cc) {
            #pragma unroll
            for (int j = 0; j < 4; ++j) {
                areg[j] = *(const short8*)(Wo_bf + (size_t)(n0 + srow + j * 32) * Cc
                                           + c0 + 64 + sc8 * 8);
                breg[j] = *(const short8*)(ctx + ((size_t)b * Lc + l0 + srow + j * 32) * Cc
                                           + c0 + 64 + sc8 * 8);
            }
        }

        #pragma unroll
        for (int ks = 0; ks < 2; ++ks) {
            short8 bf[4];
            #pragma unroll
            for (int nt = 0; nt < 4; ++nt)
                bf[nt] = *(const short8*)&Bt[(wc * 64 + nt * 16 + l16) * LDW
                                             + ks * 32 + quad * 8];
            #pragma unroll
            for (int mt = 0; mt < 4; ++mt) {
                short8 af = *(const short8*)&At[(wr * 64 + mt * 16 + l16) * LDW
                                                + ks * 32 + quad * 8];
                #pragma unroll
                for (int nt = 0; nt < 4; ++nt)
                    acc[mt][nt] = __builtin_amdgcn_mfma_f32_16x16x32_bf16(
                        af, bf[nt], acc[mt][nt], 0, 0, 0);
            }
        }
        __syncthreads();
    }

    #pragma unroll
    for (int mt = 0; mt < 4; ++mt) {
        #pragma unroll
        for (int r = 0; r < 4; ++r) {
            int n = n0 + wr * 64 + mt * 16 + quad * 4 + r;
            float bia = bo[n];
            #pragma unroll
            for (int nt = 0; nt < 4; ++nt) {
                int l = l0 + wc * 64 + nt * 16 + l16;
                size_t oidx = ((size_t)b * Cc + n) * Lc + l;
                out[oidx] = acc[mt][nt][r] + bia + ppg[oidx];
            }
        }
    }
}

// ---------------------------------------------------------------------------
extern "C" void kernel_launch(void* const* d_in, const int* in_sizes, int n_in,
                              void* d_out, int out_size, void* d_ws, size_t ws_size,
                              hipStream_t stream) {
    const float* ppg = (const float*)d_in[0];
    const float* ecg = (const float*)d_in[1];
    const float* Wq  = (const float*)d_in[2];
    const float* bq  = (const float*)d_in[3];
    const float* Wk  = (const float*)d_in[4];
    const float* bk  = (const float*)d_in[5];
    const float* Wv  = (const float*)d_in[6];
    const float* bv  = (const float*)d_in[7];
    const float* Wo  = (const float*)d_in[8];
    const float* bo  = (const float*)d_in[9];
    float* out = (float*)d_out;

    // Workspace (ushort units), lifetime-based overlays:
    //   [0, 4M)    Xt_ppg   | later Opart0 (bf16)
    //   [4M, 8M)   Xt_ecg   | later Opart1 (bf16)
    //   [8M, 9M)   Wbf
    //   [9M, 13M)  Qw
    //   [13M, 17M) Kw
    //   [17M, 21M) Vtw
    //   [21M, 25M) ctx (bf16, fresh region — no overlay with live attn data)
    //   [25M, +256K) lpart (fp32)
    //   then ctr (256 ints)
    unsigned short* base   = (unsigned short*)d_ws;
    const size_t M = 1024 * 1024;
    unsigned short* Xt_ppg = base;
    unsigned short* Xt_ecg = base + 4 * M;
    unsigned short* Wbf    = base + 8 * M;
    unsigned short* Qw     = base + 9 * M;
    unsigned short* Kw     = base + 13 * M;
    unsigned short* Vtw    = base + 17 * M;
    unsigned short* ctx    = base + 21 * M;
    float* lpart = (float*)(base + 25 * M);
    int*   ctr   = (int*)(base + 25 * M + 262144);
    unsigned short* Opart0 = base;             // overlays Xt_ppg (dead)
    unsigned short* Opart1 = base + 4 * M;     // overlays Xt_ecg (dead)

    hipMemsetAsync(ctr, 0, 32 * 8 * sizeof(int), stream);

    prep_kernel<<<2560, 256, 0, stream>>>(ppg, ecg, Wq, Wk, Wv, Wo,
                                          Xt_ppg, Xt_ecg, Wbf);

    dim3 g1(Lc / 128, Cc / 128, 3 * Bc);
    proj_kernel<<<g1, 256, 0, stream>>>(Xt_ppg, Xt_ecg, Wbf, bq, bk, bv,
                                        Qw, Kw, Vtw);

    dim3 g2(Lc / 256, Bc * Hc, 2);
    attn_mfma_kernel<<<g2, 256, 0, stream>>>(Qw, Kw, Vtw, Opart0, Opart1,
                                             lpart, ctx, ctr);

    dim3 g3(Lc / 128, Cc / 128, Bc);
    outproj_kernel<<<g3, 256, 0, stream>>>(ctx, Wbf + (size_t)3 * Cc * Cc,
                                           bo, ppg, out);
}

// Round 9
// 183.974 us; speedup vs baseline: 1.5815x; 1.5815x over previous
//
#include <hip/hip_runtime.h>
#include <hip/hip_bf16.h>

// Problem constants
static constexpr int Bc = 4;
static constexpr int Lc = 2048;
static constexpr int Cc = 512;     // FEATURE_DIM
static constexpr int Hc = 8;       // NUM_HEADS
static constexpr int Dc = 64;      // HEAD_DIM

using short8  = __attribute__((ext_vector_type(8))) short;
using float4v = __attribute__((ext_vector_type(4))) float;

static __device__ __forceinline__ unsigned short f2bf(float f) {
    __hip_bfloat16 h = __float2bfloat16(f);   // RNE
    return *reinterpret_cast<unsigned short*>(&h);
}
static __device__ __forceinline__ float bf2f(unsigned short u) {
    return __uint_as_float(((unsigned int)u) << 16);
}

// ---------------------------------------------------------------------------
// Kernel 0: prep (unchanged from R7).
// ---------------------------------------------------------------------------
__global__ __launch_bounds__(256) void prep_kernel(
    const float* __restrict__ ppg, const float* __restrict__ ecg,
    const float* __restrict__ Wq, const float* __restrict__ Wk,
    const float* __restrict__ Wv, const float* __restrict__ Wo,
    unsigned short* __restrict__ Xt_ppg, unsigned short* __restrict__ Xt_ecg,
    unsigned short* __restrict__ Wbf)
{
    __shared__ float Ts[64 * 69];
    const int task = blockIdx.x;
    const int tid  = threadIdx.x;

    if (task < 2048) {
        const int src = task >> 10;
        const int rem = task & 1023;
        const int b   = rem >> 8;
        const int c0  = ((rem >> 5) & 7) * 64;
        const int l0  = (rem & 31) * 64;
        const float* X = src ? ecg : ppg;
        unsigned short* Xt = src ? Xt_ecg : Xt_ppg;

        #pragma unroll
        for (int j = 0; j < 4; ++j) {
            int idx = tid + j * 256;
            int c = idx >> 4, l4 = idx & 15;
            float4 v = *(const float4*)(X + ((size_t)b * Cc + c0 + c) * Lc + l0 + l4 * 4);
            Ts[c * 69 + l4 * 4 + 0] = v.x;
            Ts[c * 69 + l4 * 4 + 1] = v.y;
            Ts[c * 69 + l4 * 4 + 2] = v.z;
            Ts[c * 69 + l4 * 4 + 3] = v.w;
        }
        __syncthreads();
        #pragma unroll
        for (int j = 0; j < 8; ++j) {
            int u = tid + j * 256;
            int l = u >> 5, p2 = u & 31;
            float a = Ts[(2 * p2) * 69 + l];
            float bb = Ts[(2 * p2 + 1) * 69 + l];
            ushort2 pk; pk.x = f2bf(a); pk.y = f2bf(bb);
            *(ushort2*)(Xt + ((size_t)b * Lc + l0 + l) * Cc + c0 + 2 * p2) = pk;
        }
    } else {
        const int wb   = task - 2048;
        const int widx = wb >> 7;
        const float* W = widx == 0 ? Wq : widx == 1 ? Wk : widx == 2 ? Wv : Wo;
        size_t off = (size_t)(wb & 127) * 2048 + (size_t)tid * 8;
        float4 v0 = *(const float4*)(W + off);
        float4 v1 = *(const float4*)(W + off + 4);
        unsigned short pk[8] = {f2bf(v0.x), f2bf(v0.y), f2bf(v0.z), f2bf(v0.w),
                                f2bf(v1.x), f2bf(v1.y), f2bf(v1.z), f2bf(v1.w)};
        *(short8*)(Wbf + (size_t)widx * Cc * Cc + off) = *(const short8*)pk;
    }
}

// ---------------------------------------------------------------------------
// Kernel 1: Q/K/V projections (unchanged from R7).
// ---------------------------------------------------------------------------
__global__ __launch_bounds__(256) void proj_kernel(
    const unsigned short* __restrict__ Xt_ppg,
    const unsigned short* __restrict__ Xt_ecg,
    const unsigned short* __restrict__ Wbf,
    const float* __restrict__ bq, const float* __restrict__ bk,
    const float* __restrict__ bv,
    unsigned short* __restrict__ Qw, unsigned short* __restrict__ Kw,
    unsigned short* __restrict__ Vtw)
{
    constexpr int LDW = 72;
    const int z = blockIdx.z, p = z >> 2, b = z & 3;
    const int l0 = blockIdx.x * 128, n0 = blockIdx.y * 128;
    const unsigned short* X = (p == 0) ? Xt_ppg : Xt_ecg;
    const unsigned short* W = Wbf + (size_t)p * Cc * Cc;
    const float* bias = (p == 0) ? bq : (p == 1) ? bk : bv;

    const int tid = threadIdx.x, wave = tid >> 6, lane = tid & 63;
    const int l16 = lane & 15, quad = lane >> 4;
    const int wr = wave >> 1, wc = wave & 1;

    __shared__ __align__(16) unsigned short At[128 * LDW];
    __shared__ __align__(16) unsigned short Bt[128 * LDW];

    float4v acc[4][4] = {};
    short8 areg[4], breg[4];

    const int srow = tid >> 3, sc8 = tid & 7;
    #pragma unroll
    for (int j = 0; j < 4; ++j) {
        areg[j] = *(const short8*)(X + ((size_t)b * Lc + l0 + srow + j * 32) * Cc + sc8 * 8);
        breg[j] = *(const short8*)(W + (size_t)(n0 + srow + j * 32) * Cc + sc8 * 8);
    }

    for (int c0 = 0; c0 < Cc; c0 += 64) {
        #pragma unroll
        for (int j = 0; j < 4; ++j) {
            *(short8*)&At[(srow + j * 32) * LDW + sc8 * 8] = areg[j];
            *(short8*)&Bt[(srow + j * 32) * LDW + sc8 * 8] = breg[j];
        }
        __syncthreads();

        if (c0 + 64 < Cc) {
            #pragma unroll
            for (int j = 0; j < 4; ++j) {
                areg[j] = *(const short8*)(X + ((size_t)b * Lc + l0 + srow + j * 32) * Cc
                                           + c0 + 64 + sc8 * 8);
                breg[j] = *(const short8*)(W + (size_t)(n0 + srow + j * 32) * Cc
                                           + c0 + 64 + sc8 * 8);
            }
        }

        const unsigned short* Am = (p < 2) ? At : Bt;
        const unsigned short* Bm = (p < 2) ? Bt : At;

        #pragma unroll
        for (int ks = 0; ks < 2; ++ks) {
            short8 bf[4];
            #pragma unroll
            for (int nt = 0; nt < 4; ++nt)
                bf[nt] = *(const short8*)&Bm[(wc * 64 + nt * 16 + l16) * LDW
                                             + ks * 32 + quad * 8];
            #pragma unroll
            for (int mt = 0; mt < 4; ++mt) {
                short8 af = *(const short8*)&Am[(wr * 64 + mt * 16 + l16) * LDW
                                                + ks * 32 + quad * 8];
                #pragma unroll
                for (int nt = 0; nt < 4; ++nt)
                    acc[mt][nt] = __builtin_amdgcn_mfma_f32_16x16x32_bf16(
                        af, bf[nt], acc[mt][nt], 0, 0, 0);
            }
        }
        __syncthreads();
    }

    if (p < 2) {
        const float sc = (p == 0) ? 0.18033688011112042f : 1.0f;  // 0.125*log2(e)
        unsigned short* dst = (p == 0) ? Qw : Kw;
        #pragma unroll
        for (int nt = 0; nt < 4; ++nt) {
            int n = n0 + wc * 64 + nt * 16 + l16;
            int h = n >> 6, d = n & 63;
            int bh = b * Hc + h;
            float bia = bias[n];
            #pragma unroll
            for (int mt = 0; mt < 4; ++mt) {
                #pragma unroll
                for (int r = 0; r < 4; ++r) {
                    int l = l0 + wr * 64 + mt * 16 + quad * 4 + r;
                    dst[((size_t)bh * Lc + l) * Dc + d] =
                        f2bf((acc[mt][nt][r] + bia) * sc);
                }
            }
        }
    } else {
        #pragma unroll
        for (int mt = 0; mt < 4; ++mt) {
            #pragma unroll
            for (int r = 0; r < 4; ++r) {
                int n = n0 + wr * 64 + mt * 16 + quad * 4 + r;
                int h = n >> 6, d = n & 63;
                int bh = b * Hc + h;
                float bia = bias[n];
                #pragma unroll
                for (int nt = 0; nt < 4; ++nt) {
                    int l = l0 + wc * 64 + nt * 16 + l16;
                    Vtw[((size_t)bh * Dc + d) * Lc + l] = f2bf(acc[mt][nt][r] + bia);
                }
            }
        }
    }
}

// ---------------------------------------------------------------------------
// Kernel 2: flash attention, split-K over keys, q=32/wave, 128q/block,
// 2 splits (R7 structure, VGPR ~64). Partials now stored bf16.
// ---------------------------------------------------------------------------
__global__ __launch_bounds__(256, 4) void attn_mfma_kernel(
    const unsigned short* __restrict__ Qg,    // [bh][l][64], pre-scaled
    const unsigned short* __restrict__ Kg,    // [bh][l][64]
    const unsigned short* __restrict__ Vtg,   // [bh][64][l]
    unsigned short* __restrict__ O0,          // [b][l][512] bf16 partials
    unsigned short* __restrict__ O1,
    float* __restrict__ lpart)                // [2][bh][l]
{
    constexpr int LDW = 72;
    const int bh    = blockIdx.y;
    const int split = blockIdx.z;
    const int q0    = blockIdx.x * 128;
    const int tid   = threadIdx.x;
    const int wave  = tid >> 6;
    const int lane  = tid & 63;
    const int l16   = lane & 15;
    const int quad  = lane >> 4;

    __shared__ __align__(16) unsigned short Kt[64 * LDW];
    __shared__ __align__(16) unsigned short Vt[64 * LDW];
    __shared__ __align__(16) unsigned short PT[128 * LDW];  // Q stage, then P^T

    const int srow = tid >> 3, sc8 = tid & 7;

    // ---- stage Q tile (128 x 64) into PT ----
    const unsigned short* Qb = Qg + ((size_t)bh * Lc + q0) * Dc;
    #pragma unroll
    for (int j = 0; j < 4; ++j)
        *(short8*)&PT[(srow + j * 32) * LDW + sc8 * 8] =
            *(const short8*)(Qb + (srow + j * 32) * Dc + sc8 * 8);
    __syncthreads();

    // Q fragments (wave-private rows; MFMA B-operand)
    short8 qf[2][2];   // [qt][ks]
    #pragma unroll
    for (int qt = 0; qt < 2; ++qt)
        #pragma unroll
        for (int ks = 0; ks < 2; ++ks)
            qf[qt][ks] = *(const short8*)&PT[(wave * 32 + qt * 16 + l16) * LDW
                                             + ks * 32 + quad * 8];
    // PT rows wave-private hereafter (rows wave*32..wave*32+31).

    float4v O[2][4] = {};                    // [qt][dt]; rows=q, cols=d
    float lsum[2] = {0.0f, 0.0f};

    const unsigned short* Kb0 = Kg + (size_t)bh * Lc * Dc;
    const unsigned short* Vb0 = Vtg + (size_t)bh * (Dc * Lc);
    const int kbase = split * (Lc / 2);

    short8 kreg[2], vreg[2];
    #pragma unroll
    for (int j = 0; j < 2; ++j) {
        kreg[j] = *(const short8*)(Kb0 + (size_t)(kbase + srow + j * 32) * Dc + sc8 * 8);
        vreg[j] = *(const short8*)(Vb0 + (size_t)(srow + j * 32) * Lc + kbase + sc8 * 8);
    }

    for (int kc = kbase; kc < kbase + Lc / 2; kc += 64) {
        #pragma unroll
        for (int j = 0; j < 2; ++j) {
            *(short8*)&Kt[(srow + j * 32) * LDW + sc8 * 8] = kreg[j];
            *(short8*)&Vt[(srow + j * 32) * LDW + sc8 * 8] = vreg[j];
        }
        __syncthreads();

        if (kc + 64 < kbase + Lc / 2) {
            #pragma unroll
            for (int j = 0; j < 2; ++j) {
                kreg[j] = *(const short8*)(Kb0 + (size_t)(kc + 64 + srow + j * 32) * Dc
                                           + sc8 * 8);
                vreg[j] = *(const short8*)(Vb0 + (size_t)(srow + j * 32) * Lc
                                           + kc + 64 + sc8 * 8);
            }
        }

        // ---- S^T = K·Q^T : 4 key-tiles x 2 query-tiles ----
        float4v S[4][2];
        #pragma unroll
        for (int kt = 0; kt < 4; ++kt)
            #pragma unroll
            for (int qt = 0; qt < 2; ++qt)
                S[kt][qt] = (float4v){0.f, 0.f, 0.f, 0.f};
        #pragma unroll
        for (int ks = 0; ks < 2; ++ks) {
            #pragma unroll
            for (int kt = 0; kt < 4; ++kt) {
                short8 af = *(const short8*)&Kt[(kt * 16 + l16) * LDW
                                                + ks * 32 + quad * 8];
                #pragma unroll
                for (int qt = 0; qt < 2; ++qt)
                    S[kt][qt] = __builtin_amdgcn_mfma_f32_16x16x32_bf16(
                        af, qf[qt][ks], S[kt][qt], 0, 0, 0);
            }
        }

        // ---- P^T = exp2(S^T); accumulate l; store PT[q][key] ----
        #pragma unroll
        for (int qt = 0; qt < 2; ++qt) {
            #pragma unroll
            for (int kt = 0; kt < 4; ++kt) {
                float p0 = __builtin_amdgcn_exp2f(S[kt][qt][0]);
                float p1 = __builtin_amdgcn_exp2f(S[kt][qt][1]);
                float p2 = __builtin_amdgcn_exp2f(S[kt][qt][2]);
                float p3 = __builtin_amdgcn_exp2f(S[kt][qt][3]);
                lsum[qt] += (p0 + p1) + (p2 + p3);
                ushort4 pk;
                pk.x = f2bf(p0); pk.y = f2bf(p1); pk.z = f2bf(p2); pk.w = f2bf(p3);
                *(ushort4*)&PT[(wave * 32 + qt * 16 + l16) * LDW
                               + kt * 16 + quad * 4] = pk;
            }
        }

        // ---- O += P · V ----
        #pragma unroll
        for (int ks = 0; ks < 2; ++ks) {
            short8 pf[2];
            #pragma unroll
            for (int qt = 0; qt < 2; ++qt)
                pf[qt] = *(const short8*)&PT[(wave * 32 + qt * 16 + l16) * LDW
                                             + ks * 32 + quad * 8];
            #pragma unroll
            for (int dt = 0; dt < 4; ++dt) {
                short8 vf = *(const short8*)&Vt[(dt * 16 + l16) * LDW
                                                + ks * 32 + quad * 8];
                #pragma unroll
                for (int qt = 0; qt < 2; ++qt)
                    O[qt][dt] = __builtin_amdgcn_mfma_f32_16x16x32_bf16(
                        pf[qt], vf, O[qt][dt], 0, 0, 0);
            }
        }
        __syncthreads();   // all waves done with Kt/Vt before next staging
    }

    // ---- epilogue: partial l (quad-reduced) + partial O (bf16) ----
    const int b = bh >> 3, h = bh & 7;
    unsigned short* Om = split ? O1 : O0;
    float* lp = lpart + (size_t)split * (Bc * Hc) * Lc + (size_t)bh * Lc;

    #pragma unroll
    for (int qt = 0; qt < 2; ++qt) {
        float t = lsum[qt];
        t += __shfl_xor(t, 16, 64);
        t += __shfl_xor(t, 32, 64);
        if (quad == 0)
            lp[q0 + wave * 32 + qt * 16 + l16] = t;
        #pragma unroll
        for (int dt = 0; dt < 4; ++dt) {
            #pragma unroll
            for (int r = 0; r < 4; ++r) {
                int q = q0 + wave * 32 + qt * 16 + quad * 4 + r;
                Om[((size_t)b * Lc + q) * Cc + h * Dc + dt * 16 + l16] =
                    f2bf(O[qt][dt][r]);
            }
        }
    }
}

// ---------------------------------------------------------------------------
// Kernel 3: output projection with fused split-K combine. 128(l) x 128(n)
// tile, 2x2 wave quadrants. B-tile staged as (O0+O1)*inv_l -> bf16.
// D[n][l] = Wo·ctx^T; + bias + residual -> (B,C,L) fp32.
// ---------------------------------------------------------------------------
__global__ __launch_bounds__(256) void outproj_kernel(
    const unsigned short* __restrict__ O0, const unsigned short* __restrict__ O1,
    const float* __restrict__ lpart,
    const unsigned short* __restrict__ Wo_bf,
    const float* __restrict__ bo, const float* __restrict__ ppg,
    float* __restrict__ out)
{
    constexpr int LDW = 72;
    const int b = blockIdx.z;
    const int l0 = blockIdx.x * 128, n0 = blockIdx.y * 128;
    const int tid = threadIdx.x, wave = tid >> 6, lane = tid & 63;
    const int l16 = lane & 15, quad = lane >> 4;
    const int wr = wave >> 1, wc = wave & 1;

    __shared__ __align__(16) unsigned short At[128 * LDW];  // Wo tile [n][c]
    __shared__ __align__(16) unsigned short Bt[128 * LDW];  // ctx tile [l][c]

    float4v acc[4][4] = {};                  // [mt(n)][nt(l)]
    const int srow = tid >> 3, sc8 = tid & 7;
    const size_t lplane = (size_t)(Bc * Hc) * Lc;

    for (int c0 = 0; c0 < Cc; c0 += 64) {
        const int h = c0 >> 6;
        const float* lp0 = lpart + (size_t)(b * Hc + h) * Lc;
        const float* lp1 = lp0 + lplane;

        #pragma unroll
        for (int j = 0; j < 4; ++j) {
            int row = srow + j * 32;
            // A: Wo tile
            *(short8*)&At[row * LDW + sc8 * 8] =
                *(const short8*)(Wo_bf + (size_t)(n0 + row) * Cc + c0 + sc8 * 8);
            // B: combined context tile
            int l = l0 + row;
            float inv = 1.0f / (lp0[l] + lp1[l]);
            size_t off = ((size_t)b * Lc + l) * Cc + c0 + sc8 * 8;
            short8 a8 = *(const short8*)(O0 + off);
            short8 b8 = *(const short8*)(O1 + off);
            unsigned short pk[8];
            #pragma unroll
            for (int e = 0; e < 8; ++e) {
                unsigned short ua = ((const unsigned short*)&a8)[e];
                unsigned short ub = ((const unsigned short*)&b8)[e];
                pk[e] = f2bf((bf2f(ua) + bf2f(ub)) * inv);
            }
            *(short8*)&Bt[row * LDW + sc8 * 8] = *(const short8*)pk;
        }
        __syncthreads();

        #pragma unroll
        for (int ks = 0; ks < 2; ++ks) {
            short8 bfr[4];
            #pragma unroll
            for (int nt = 0; nt < 4; ++nt)
                bfr[nt] = *(const short8*)&Bt[(wc * 64 + nt * 16 + l16) * LDW
                                              + ks * 32 + quad * 8];
            #pragma unroll
            for (int mt = 0; mt < 4; ++mt) {
                short8 af = *(const short8*)&At[(wr * 64 + mt * 16 + l16) * LDW
                                                + ks * 32 + quad * 8];
                #pragma unroll
                for (int nt = 0; nt < 4; ++nt)
                    acc[mt][nt] = __builtin_amdgcn_mfma_f32_16x16x32_bf16(
                        af, bfr[nt], acc[mt][nt], 0, 0, 0);
            }
        }
        __syncthreads();
    }

    #pragma unroll
    for (int mt = 0; mt < 4; ++mt) {
        #pragma unroll
        for (int r = 0; r < 4; ++r) {
            int n = n0 + wr * 64 + mt * 16 + quad * 4 + r;
            float bia = bo[n];
            #pragma unroll
            for (int nt = 0; nt < 4; ++nt) {
                int l = l0 + wc * 64 + nt * 16 + l16;
                size_t oidx = ((size_t)b * Cc + n) * Lc + l;
                out[oidx] = acc[mt][nt][r] + bia + ppg[oidx];
            }
        }
    }
}

// ---------------------------------------------------------------------------
extern "C" void kernel_launch(void* const* d_in, const int* in_sizes, int n_in,
                              void* d_out, int out_size, void* d_ws, size_t ws_size,
                              hipStream_t stream) {
    const float* ppg = (const float*)d_in[0];
    const float* ecg = (const float*)d_in[1];
    const float* Wq  = (const float*)d_in[2];
    const float* bq  = (const float*)d_in[3];
    const float* Wk  = (const float*)d_in[4];
    const float* bk  = (const float*)d_in[5];
    const float* Wv  = (const float*)d_in[6];
    const float* bv  = (const float*)d_in[7];
    const float* Wo  = (const float*)d_in[8];
    const float* bo  = (const float*)d_in[9];
    float* out = (float*)d_out;

    // Workspace (ushort units), lifetime-based overlays:
    //   [0, 4M)    Xt_ppg   | later Opart0 (bf16 [b][l][c])
    //   [4M, 8M)   Xt_ecg   | later Opart1 (bf16)
    //   [8M, 9M)   Wbf
    //   [9M, 13M)  Qw
    //   [13M, 17M) Kw
    //   [17M, 21M) Vtw
    //   [21M, +512KB) lpart (fp32 [2][bh][l])
    unsigned short* base   = (unsigned short*)d_ws;
    const size_t M = 1024 * 1024;
    unsigned short* Xt_ppg = base;
    unsigned short* Xt_ecg = base + 4 * M;
    unsigned short* Wbf    = base + 8 * M;
    unsigned short* Qw     = base + 9 * M;
    unsigned short* Kw     = base + 13 * M;
    unsigned short* Vtw    = base + 17 * M;
    float* lpart = (float*)(base + 21 * M);
    unsigned short* Opart0 = base;             // overlays Xt_ppg (dead after proj)
    unsigned short* Opart1 = base + 4 * M;     // overlays Xt_ecg (dead after proj)

    prep_kernel<<<2560, 256, 0, stream>>>(ppg, ecg, Wq, Wk, Wv, Wo,
                                          Xt_ppg, Xt_ecg, Wbf);

    dim3 g1(Lc / 128, Cc / 128, 3 * Bc);
    proj_kernel<<<g1, 256, 0, stream>>>(Xt_ppg, Xt_ecg, Wbf, bq, bk, bv,
                                        Qw, Kw, Vtw);

    dim3 g2(Lc / 128, Bc * Hc, 2);
    attn_mfma_kernel<<<g2, 256, 0, stream>>>(Qw, Kw, Vtw, Opart0, Opart1, lpart);

    dim3 g3(Lc / 128, Cc / 128, Bc);
    outproj_kernel<<<g3, 256, 0, stream>>>(Opart0, Opart1, lpart,
                                           Wbf + (size_t)3 * Cc * Cc,
                                           bo, ppg, out);
}